// Round 6
// baseline (824.041 us; speedup 1.0000x reference)
//
#include <hip/hip_runtime.h>

#define NUM_CN   25000
#define NUM_VN   50000
#define NUM_E    200000
#define D_EMBED  16
#define D_HIDDEN 32
#define D_MSG    16
#define BATCH    16

// ---------------------------------------------------------------------------
// Workspace layout (int units) — 54.41 MB total (proven available):
#define WS_IDS_X   0           // 200000  (stores FROM node ids, CSR order)
#define WS_IDS_Z   200000      // 200000
#define WS_OFF_X   400000      // 50001
#define WS_OFF_Z   450001      // 50001
#define WS_CNT_X   500002      // 50000
#define WS_CNT_Z   550002      // 50000
#define WS_CUR_X   600002      // 50000 -> bits_x after fill
#define WS_CUR_Z   650002      // 50000 -> bits_z after fill
#define WS_INCL_X  700002      // 51200
#define WS_INCL_Z  751202      // 51200
#define WS_PSUM    802402      // 128
#define WS_BASE    802530      // 128
#define WS_A1X     802816      // 6400000 ints = 25.6 MB bf16
#define WS_A1Z     7202816     // 6400000
#define SCAN_CHUNKS 49

// ---- proven pre-pipeline (exact baseline restore; R4's 2-CU scan was the
// ~+170us regression — coalesced 98-workgroup version is the keeper) -------
__global__ __launch_bounds__(256) void hist_kernel(
    const int* __restrict__ ti_x, const int* __restrict__ ti_z,
    int* __restrict__ cnt_x, int* __restrict__ cnt_z)
{
    int e = blockIdx.x * 256 + threadIdx.x;
    if (e >= NUM_E) return;
    atomicAdd(&cnt_x[ti_x[e]], 1);
    atomicAdd(&cnt_z[ti_z[e]], 1);
}

__global__ __launch_bounds__(1024) void scan1_kernel(
    const int* __restrict__ cnt_x, const int* __restrict__ cnt_z,
    int* __restrict__ incl_x, int* __restrict__ incl_z,
    int* __restrict__ psum)
{
    __shared__ int s[1024];
    const int ch  = blockIdx.y;
    const int blk = blockIdx.x;
    const int t   = threadIdx.x;
    const int gid = blk * 1024 + t;
    const int* cnt  = ch ? cnt_z  : cnt_x;
    int*       incl = ch ? incl_z : incl_x;
    int v = (gid < NUM_VN) ? cnt[gid] : 0;
    s[t] = v;
    __syncthreads();
#pragma unroll
    for (int d = 1; d < 1024; d <<= 1) {
        int x = 0;
        if (t >= d) x = s[t - d];
        __syncthreads();
        if (t >= d) s[t] += x;
        __syncthreads();
    }
    incl[gid] = s[t];
    if (t == 1023) psum[ch * 64 + blk] = s[1023];
}

__global__ void scan2_kernel(const int* __restrict__ psum, int* __restrict__ base)
{
    int ch = threadIdx.x;
    if (ch >= 2) return;
    int run = 0;
    for (int i = 0; i < SCAN_CHUNKS; ++i) {
        base[ch * 64 + i] = run;
        run += psum[ch * 64 + i];
    }
}

__global__ __launch_bounds__(1024) void scan3_kernel(
    const int* __restrict__ cnt_x, const int* __restrict__ cnt_z,
    const int* __restrict__ incl_x, const int* __restrict__ incl_z,
    const int* __restrict__ base,
    int* __restrict__ off_x, int* __restrict__ off_z,
    int* __restrict__ cur_x, int* __restrict__ cur_z)
{
    const int ch  = blockIdx.y;
    const int blk = blockIdx.x;
    const int t   = threadIdx.x;
    const int i   = blk * 1024 + t;
    if (i >= NUM_VN) return;
    const int* cnt  = ch ? cnt_z  : cnt_x;
    const int* incl = ch ? incl_z : incl_x;
    int*       off  = ch ? off_z  : off_x;
    int*       cur  = ch ? cur_z  : cur_x;
    int bs = base[ch * 64 + blk];
    int iv = incl[i];
    off[i + 1] = bs + iv;
    cur[i]     = bs + iv - cnt[i];
    if (i == 0) off[0] = 0;
}

// fill: CSR slot stores the FROM node id directly.
__global__ __launch_bounds__(256) void fill_kernel(
    const int* __restrict__ ti_x, const int* __restrict__ ti_z,
    const int* __restrict__ fi_x, const int* __restrict__ fi_z,
    int* __restrict__ cur_x, int* __restrict__ cur_z,
    int* __restrict__ ids_x, int* __restrict__ ids_z)
{
    int e = blockIdx.x * 256 + threadIdx.x;
    if (e >= NUM_E) return;
    int px = atomicAdd(&cur_x[ti_x[e]], 1);
    ids_x[px] = fi_x[e];
    int pz = atomicAdd(&cur_z[ti_z[e]], 1);
    ids_z[pz] = fi_z[e];
}

// syn bitmask: bits[cn] bit b = syn[b,cn]. Runs AFTER fill (targets dead cur_*).
__global__ __launch_bounds__(256) void pack_bits_kernel(
    const int* __restrict__ syn_x, const int* __restrict__ syn_z,
    unsigned* __restrict__ bits_x, unsigned* __restrict__ bits_z)
{
    int cn = blockIdx.x * 256 + threadIdx.x;
    if (cn >= NUM_CN) return;
    unsigned wx = 0, wz = 0;
#pragma unroll
    for (int b = 0; b < BATCH; ++b) {
        wx |= (unsigned)(syn_x[b * NUM_CN + cn] & 1) << b;
        wz |= (unsigned)(syn_z[b * NUM_CN + cn] & 1) << b;
    }
    bits_x[cn] = wx;
    bits_z[cn] = wz;
}

// ---------------------------------------------------------------------------
__device__ __forceinline__ unsigned pack_bf16(float a, float b) {
    unsigned ua = __float_as_uint(a); ua += 0x7fff + ((ua >> 16) & 1);
    unsigned ub = __float_as_uint(b); ub += 0x7fff + ((ub >> 16) & 1);
    return (ua >> 16) | (ub & 0xffff0000u);
}

// a1[ch][cn][b][32] = h_from[b,cn,:] @ W1[0:16,:]  bf16 lane-interleaved:
// uint4 #(p*16+b) of a node's 64-uint4 block holds hidden [8p,8p+8) for
// batch b. MASK FOLDED IN (proven R1/R2/R4, absmax unchanged): syn==0 rows
// are bf16 -inf so gather-side relu(a1+act)==0 == mask*relu(...).
__global__ __launch_bounds__(256) void a1_kernel(
    const float* __restrict__ h_from_x, const float* __restrict__ h_from_z,
    const float* __restrict__ Wx1, const float* __restrict__ Wz1,
    const unsigned* __restrict__ bits_x, const unsigned* __restrict__ bits_z,
    uint4* __restrict__ a1x, uint4* __restrict__ a1z)
{
    int t = blockIdx.x * 256 + threadIdx.x;
    if (t >= NUM_CN * BATCH) return;
    const int ch = blockIdx.y;
    const int b  = t & 15;
    const int cn = t >> 4;
    const float* hsrc = (ch ? h_from_z : h_from_x) + ((size_t)b * NUM_CN + cn) * D_EMBED;
    const float* W1   = ch ? Wz1 : Wx1;
    const unsigned mw = (ch ? bits_z : bits_x)[cn];
    const bool on = (mw >> b) & 1u;
    uint4* dst = (ch ? a1z : a1x) + (size_t)cn * 64;

    float hf[D_EMBED];
#pragma unroll
    for (int i = 0; i < 4; ++i) {
        float4 v = ((const float4*)hsrc)[i];
        hf[4 * i + 0] = v.x; hf[4 * i + 1] = v.y;
        hf[4 * i + 2] = v.z; hf[4 * i + 3] = v.w;
    }
    float a[D_HIDDEN];
#pragma unroll
    for (int j = 0; j < D_HIDDEN; ++j) a[j] = 0.0f;
#pragma unroll
    for (int i = 0; i < D_EMBED; ++i) {
        const float fi = hf[i];
#pragma unroll
        for (int j = 0; j < D_HIDDEN; ++j)
            a[j] = fmaf(fi, W1[i * D_HIDDEN + j], a[j]);
    }
    unsigned u[16];
#pragma unroll
    for (int j = 0; j < 16; ++j)
        u[j] = on ? pack_bf16(a[2 * j], a[2 * j + 1]) : 0xFF80FF80u;
#pragma unroll
    for (int p = 0; p < 4; ++p) {
        uint4 q;
        q.x = u[4 * p + 0]; q.y = u[4 * p + 1];
        q.z = u[4 * p + 2]; q.w = u[4 * p + 3];
        dst[p * 16 + b] = q;
    }
}

// ---------------------------------------------------------------------------
// HALF-SPLIT gather. Thread = (n, h, b), lane = (n&1)*32 + h*16 + b; half h
// owns hidden [16h, 16h+16). Per-thread accumulator state halves to 32
// floats (act[8]f2 + hacc[8]f2); true liveness ~55 regs so the (256,8) pin
// (cap 64, 8 waves/SIMD tier) has HEADROOM — unlike R0 (liveness 110 vs cap
// 64) / R2 (90 vs 64) which spilled catastrophically. Wave = 2 nodes (less
// trip divergence than baseline's 4). Single-edge loop (R4: 2-edge unroll
// regressed 155->171 via VGPR 76->92). Cross-half combine: one shfl_xor(16)
// per channel; each half packs+writes ONLY its own channel immediately so
// nothing extra is live across the z edge loop.
__device__ __forceinline__ void channel_half(
    const float* __restrict__ ht_slot, int n, int h, int b,
    const int* __restrict__ off, const int* __restrict__ ids,
    const uint4* __restrict__ a1,
    const float* __restrict__ W1, const float* __restrict__ W2,
    float* __restrict__ m)   // out: full 16-wide message (all lanes)
{
    // act = slice [16h,16h+16) of ht @ W1[16:32]; ht reloaded per channel
    // (L1-hot) instead of held live.
    float2 act[8];
#pragma unroll
    for (int p = 0; p < 8; ++p) { act[p].x = 0.0f; act[p].y = 0.0f; }
#pragma unroll
    for (int i4 = 0; i4 < 4; ++i4) {
        float4 v = ((const float4*)ht_slot)[i4];
        float hv[4] = {v.x, v.y, v.z, v.w};
#pragma unroll
        for (int j = 0; j < 4; ++j) {
            const float fi = hv[j];
            const float* w = W1 + (D_EMBED + 4 * i4 + j) * D_HIDDEN + 16 * h;
#pragma unroll
            for (int p = 0; p < 8; ++p) {
                act[p].x = fmaf(fi, w[2 * p],     act[p].x);
                act[p].y = fmaf(fi, w[2 * p + 1], act[p].y);
            }
        }
    }

    float2 hacc[8];
#pragma unroll
    for (int p = 0; p < 8; ++p) { hacc[p].x = 0.0f; hacc[p].y = 0.0f; }

    // this thread's 2 uint4s of a node block: indices h*32+b and h*32+b+16
    const uint4* aL = a1 + h * 32 + b;
    const int ks = off[n], ke = off[n + 1];
    for (int k = ks; k < ke; ++k) {
        const uint4* pa = aL + (size_t)ids[k] * 64;
        uint4 q0 = pa[0], q1 = pa[16];
        unsigned uu[8] = {q0.x, q0.y, q0.z, q0.w,
                          q1.x, q1.y, q1.z, q1.w};
#pragma unroll
        for (int p = 0; p < 8; ++p) {
            float lo = __uint_as_float(uu[p] << 16);
            float hi = __uint_as_float(uu[p] & 0xffff0000u);
            hacc[p].x += fmaxf(act[p].x + lo, 0.0f);
            hacc[p].y += fmaxf(act[p].y + hi, 0.0f);
        }
    }

    // partial message over this half's 16 hidden rows of W2, then butterfly
#pragma unroll
    for (int j = 0; j < D_MSG; ++j) m[j] = 0.0f;
#pragma unroll
    for (int p = 0; p < 8; ++p) {
        const float* w0 = W2 + (16 * h + 2 * p) * D_MSG;
        const float* w1 = w0 + D_MSG;
        const float h0 = hacc[p].x, h1 = hacc[p].y;
#pragma unroll
        for (int j = 0; j < D_MSG; ++j)
            m[j] = fmaf(h0, w0[j], fmaf(h1, w1[j], m[j]));
    }
#pragma unroll
    for (int j = 0; j < D_MSG; ++j) m[j] += __shfl_xor(m[j], 16, 64);
}

__global__ __launch_bounds__(256, 8) void gather_kernel(
    const float* __restrict__ h_to,
    const int* __restrict__ off_x, const int* __restrict__ ids_x,
    const int* __restrict__ off_z, const int* __restrict__ ids_z,
    const uint4* __restrict__ a1x, const uint4* __restrict__ a1z,
    const float* __restrict__ Wx1, const float* __restrict__ Wx2,
    const float* __restrict__ Wz1, const float* __restrict__ Wz2,
    uint4* __restrict__ out_m)
{
    const int t = blockIdx.x * 256 + threadIdx.x;   // grid exact: NUM_VN*32
    const int b = t & 15;
    const int h = (t >> 4) & 1;
    const int n = t >> 5;
    const size_t slot = (size_t)b * NUM_VN + n;
    const float* ht_slot = h_to + slot * D_EMBED;
    uint4* dst = out_m + slot * 4;

    float m[D_MSG];

    // ---- channel X; h=0 lanes pack+store mx immediately, m then dies ----
    channel_half(ht_slot, n, h, b, off_x, ids_x, a1x, Wx1, Wx2, m);
    if (h == 0) {
        uint4 q;
        q.x = pack_bf16(m[0], m[1]); q.y = pack_bf16(m[2], m[3]);
        q.z = pack_bf16(m[4], m[5]); q.w = pack_bf16(m[6], m[7]);
        dst[0] = q;
        q.x = pack_bf16(m[8],  m[9]);  q.y = pack_bf16(m[10], m[11]);
        q.z = pack_bf16(m[12], m[13]); q.w = pack_bf16(m[14], m[15]);
        dst[1] = q;
    }

    // ---- channel Z; h=1 lanes pack+store mz ----
    channel_half(ht_slot, n, h, b, off_z, ids_z, a1z, Wz1, Wz2, m);
    if (h == 1) {
        uint4 q;
        q.x = pack_bf16(m[0], m[1]); q.y = pack_bf16(m[2], m[3]);
        q.z = pack_bf16(m[4], m[5]); q.w = pack_bf16(m[6], m[7]);
        dst[2] = q;
        q.x = pack_bf16(m[8],  m[9]);  q.y = pack_bf16(m[10], m[11]);
        q.z = pack_bf16(m[12], m[13]); q.w = pack_bf16(m[14], m[15]);
        dst[3] = q;
    }
}

// node MLP: reads its own slot {mx|mz} + h_to, computes 48->32(relu)->16,
// overwrites the slot with the final fp32 output (same thread owns both).
__global__ __launch_bounds__(256) void node_kernel(
    const float* __restrict__ h_to,
    const float* __restrict__ We1, const float* __restrict__ We2,
    float* out)
{
    const int t = blockIdx.x * 256 + threadIdx.x;
    if (t >= NUM_VN * BATCH) return;
    const int b = t & (BATCH - 1);
    const int n = t >> 4;
    const size_t slot = (size_t)b * NUM_VN + n;

    const uint4* pm = (const uint4*)out + slot * 4;
    uint4 q0 = pm[0], q1 = pm[1], q2 = pm[2], q3 = pm[3];
    unsigned uu[16] = {q0.x, q0.y, q0.z, q0.w,
                       q1.x, q1.y, q1.z, q1.w,
                       q2.x, q2.y, q2.z, q2.w,
                       q3.x, q3.y, q3.z, q3.w};
    float f[48];
#pragma unroll
    for (int p = 0; p < 16; ++p) {
        f[2 * p]     = __uint_as_float(uu[p] << 16);
        f[2 * p + 1] = __uint_as_float(uu[p] & 0xffff0000u);
    }
#pragma unroll
    for (int i = 0; i < 4; ++i) {
        float4 v = ((const float4*)(h_to + slot * D_EMBED))[i];
        f[32 + 4 * i + 0] = v.x; f[32 + 4 * i + 1] = v.y;
        f[32 + 4 * i + 2] = v.z; f[32 + 4 * i + 3] = v.w;
    }

    float2 hid[16];
#pragma unroll
    for (int p = 0; p < 16; ++p) { hid[p].x = 0.0f; hid[p].y = 0.0f; }
#pragma unroll
    for (int i = 0; i < 48; ++i) {
        const float fi = f[i];
        const float* w = We1 + i * D_HIDDEN;
#pragma unroll
        for (int p = 0; p < 16; ++p) {
            hid[p].x = fmaf(fi, w[2 * p],     hid[p].x);
            hid[p].y = fmaf(fi, w[2 * p + 1], hid[p].y);
        }
    }
#pragma unroll
    for (int p = 0; p < 16; ++p) {
        hid[p].x = fmaxf(hid[p].x, 0.0f);
        hid[p].y = fmaxf(hid[p].y, 0.0f);
    }

    float o[D_EMBED];
#pragma unroll
    for (int k = 0; k < D_EMBED; ++k) o[k] = 0.0f;
#pragma unroll
    for (int p = 0; p < 16; ++p) {
        const float h0 = hid[p].x, h1 = hid[p].y;
        const float* w0 = We2 + (2 * p) * D_EMBED;
        const float* w1 = We2 + (2 * p + 1) * D_EMBED;
#pragma unroll
        for (int k = 0; k < D_EMBED; ++k)
            o[k] = fmaf(h0, w0[k], fmaf(h1, w1[k], o[k]));
    }

#pragma unroll
    for (int i = 0; i < 4; ++i) {
        float4 v;
        v.x = o[4 * i + 0]; v.y = o[4 * i + 1];
        v.z = o[4 * i + 2]; v.w = o[4 * i + 3];
        ((float4*)(out + slot * D_EMBED))[i] = v;
    }
}

// ---------------------------------------------------------------------------
extern "C" void kernel_launch(void* const* d_in, const int* in_sizes, int n_in,
                              void* d_out, int out_size, void* d_ws, size_t ws_size,
                              hipStream_t stream) {
    const float* h_from_x = (const float*)d_in[0];
    const float* h_from_z = (const float*)d_in[1];
    const float* h_to     = (const float*)d_in[2];
    const int*   syn_x    = (const int*)d_in[3];
    const int*   syn_z    = (const int*)d_in[4];
    const int*   fi_x     = (const int*)d_in[5];
    const int*   ti_x     = (const int*)d_in[6];
    const int*   fi_z     = (const int*)d_in[7];
    const int*   ti_z     = (const int*)d_in[8];
    const float* Wx1      = (const float*)d_in[9];
    const float* Wx2      = (const float*)d_in[10];
    const float* Wz1      = (const float*)d_in[11];
    const float* Wz2      = (const float*)d_in[12];
    const float* We1      = (const float*)d_in[13];
    const float* We2      = (const float*)d_in[14];

    int* ws = (int*)d_ws;
    int* ids_x  = ws + WS_IDS_X;
    int* ids_z  = ws + WS_IDS_Z;
    int* off_x  = ws + WS_OFF_X;
    int* off_z  = ws + WS_OFF_Z;
    int* cnt_x  = ws + WS_CNT_X;
    int* cnt_z  = ws + WS_CNT_Z;
    int* cur_x  = ws + WS_CUR_X;
    int* cur_z  = ws + WS_CUR_Z;
    int* incl_x = ws + WS_INCL_X;
    int* incl_z = ws + WS_INCL_Z;
    int* psum   = ws + WS_PSUM;
    int* base   = ws + WS_BASE;
    uint4* a1x  = (uint4*)(ws + WS_A1X);
    uint4* a1z  = (uint4*)(ws + WS_A1Z);

    // cur_* are dead after fill -> reuse as syndrome bitmasks
    unsigned* bits_x = (unsigned*)cur_x;
    unsigned* bits_z = (unsigned*)cur_z;

    hipMemsetAsync(cnt_x, 0, 2 * NUM_VN * sizeof(int), stream);

    hist_kernel<<<dim3((NUM_E + 255) / 256), dim3(256), 0, stream>>>(
        ti_x, ti_z, cnt_x, cnt_z);
    scan1_kernel<<<dim3(SCAN_CHUNKS, 2), dim3(1024), 0, stream>>>(
        cnt_x, cnt_z, incl_x, incl_z, psum);
    scan2_kernel<<<dim3(1), dim3(64), 0, stream>>>(psum, base);
    scan3_kernel<<<dim3(SCAN_CHUNKS, 2), dim3(1024), 0, stream>>>(
        cnt_x, cnt_z, incl_x, incl_z, base, off_x, off_z, cur_x, cur_z);
    fill_kernel<<<dim3((NUM_E + 255) / 256), dim3(256), 0, stream>>>(
        ti_x, ti_z, fi_x, fi_z, cur_x, cur_z, ids_x, ids_z);
    pack_bits_kernel<<<dim3((NUM_CN + 255) / 256), dim3(256), 0, stream>>>(
        syn_x, syn_z, bits_x, bits_z);

    a1_kernel<<<dim3((NUM_CN * BATCH + 255) / 256, 2), dim3(256), 0, stream>>>(
        h_from_x, h_from_z, Wx1, Wz1, bits_x, bits_z, a1x, a1z);

    gather_kernel<<<dim3((NUM_VN * 2 * BATCH) / 256), dim3(256), 0, stream>>>(
        h_to, off_x, ids_x, off_z, ids_z, a1x, a1z,
        Wx1, Wx2, Wz1, Wz2, (uint4*)d_out);

    node_kernel<<<dim3((NUM_VN * BATCH) / 256), dim3(256), 0, stream>>>(
        h_to, We1, We2, (float*)d_out);
}

// Round 7
// 467.194 us; speedup vs baseline: 1.7638x; 1.7638x over previous
//
#include <hip/hip_runtime.h>

#define NUM_CN   25000
#define NUM_VN   50000
#define NUM_E    200000
#define D_EMBED  16
#define D_HIDDEN 32
#define D_MSG    16
#define BATCH    16

// ---------------------------------------------------------------------------
// Workspace layout (int units) — 54.41 MB total (proven available):
#define WS_IDS_X   0           // 200000  (stores FROM node ids, CSR order)
#define WS_IDS_Z   200000      // 200000
#define WS_OFF_X   400000      // 50001
#define WS_OFF_Z   450001      // 50001
#define WS_CNT_X   500002      // 50000
#define WS_CNT_Z   550002      // 50000
#define WS_CUR_X   600002      // 50000 -> bits_x after fill
#define WS_CUR_Z   650002      // 50000 -> bits_z after fill
#define WS_INCL_X  700002      // 51200
#define WS_INCL_Z  751202      // 51200
#define WS_PSUM    802402      // 128
#define WS_BASE    802530      // 128
#define WS_A1X     802816      // 6400000 ints = 25.6 MB bf16
#define WS_A1Z     7202816     // 6400000
#define SCAN_CHUNKS 49

// ---- EXACT baseline pre-pipeline (416us total, proven) --------------------
__global__ __launch_bounds__(256) void hist_kernel(
    const int* __restrict__ ti_x, const int* __restrict__ ti_z,
    int* __restrict__ cnt_x, int* __restrict__ cnt_z)
{
    int e = blockIdx.x * 256 + threadIdx.x;
    if (e >= NUM_E) return;
    atomicAdd(&cnt_x[ti_x[e]], 1);
    atomicAdd(&cnt_z[ti_z[e]], 1);
}

__global__ __launch_bounds__(1024) void scan1_kernel(
    const int* __restrict__ cnt_x, const int* __restrict__ cnt_z,
    int* __restrict__ incl_x, int* __restrict__ incl_z,
    int* __restrict__ psum)
{
    __shared__ int s[1024];
    const int ch  = blockIdx.y;
    const int blk = blockIdx.x;
    const int t   = threadIdx.x;
    const int gid = blk * 1024 + t;
    const int* cnt  = ch ? cnt_z  : cnt_x;
    int*       incl = ch ? incl_z : incl_x;
    int v = (gid < NUM_VN) ? cnt[gid] : 0;
    s[t] = v;
    __syncthreads();
#pragma unroll
    for (int d = 1; d < 1024; d <<= 1) {
        int x = 0;
        if (t >= d) x = s[t - d];
        __syncthreads();
        if (t >= d) s[t] += x;
        __syncthreads();
    }
    incl[gid] = s[t];
    if (t == 1023) psum[ch * 64 + blk] = s[1023];
}

__global__ void scan2_kernel(const int* __restrict__ psum, int* __restrict__ base)
{
    int ch = threadIdx.x;
    if (ch >= 2) return;
    int run = 0;
    for (int i = 0; i < SCAN_CHUNKS; ++i) {
        base[ch * 64 + i] = run;
        run += psum[ch * 64 + i];
    }
}

__global__ __launch_bounds__(1024) void scan3_kernel(
    const int* __restrict__ cnt_x, const int* __restrict__ cnt_z,
    const int* __restrict__ incl_x, const int* __restrict__ incl_z,
    const int* __restrict__ base,
    int* __restrict__ off_x, int* __restrict__ off_z,
    int* __restrict__ cur_x, int* __restrict__ cur_z)
{
    const int ch  = blockIdx.y;
    const int blk = blockIdx.x;
    const int t   = threadIdx.x;
    const int i   = blk * 1024 + t;
    if (i >= NUM_VN) return;
    const int* cnt  = ch ? cnt_z  : cnt_x;
    const int* incl = ch ? incl_z : incl_x;
    int*       off  = ch ? off_z  : off_x;
    int*       cur  = ch ? cur_z  : cur_x;
    int bs = base[ch * 64 + blk];
    int iv = incl[i];
    off[i + 1] = bs + iv;
    cur[i]     = bs + iv - cnt[i];
    if (i == 0) off[0] = 0;
}

// fill: CSR slot stores the FROM node id directly.
__global__ __launch_bounds__(256) void fill_kernel(
    const int* __restrict__ ti_x, const int* __restrict__ ti_z,
    const int* __restrict__ fi_x, const int* __restrict__ fi_z,
    int* __restrict__ cur_x, int* __restrict__ cur_z,
    int* __restrict__ ids_x, int* __restrict__ ids_z)
{
    int e = blockIdx.x * 256 + threadIdx.x;
    if (e >= NUM_E) return;
    int px = atomicAdd(&cur_x[ti_x[e]], 1);
    ids_x[px] = fi_x[e];
    int pz = atomicAdd(&cur_z[ti_z[e]], 1);
    ids_z[pz] = fi_z[e];
}

// syn bitmask: bits[cn] bit b = syn[b,cn]. Runs AFTER fill (targets dead cur_*).
__global__ __launch_bounds__(256) void pack_bits_kernel(
    const int* __restrict__ syn_x, const int* __restrict__ syn_z,
    unsigned* __restrict__ bits_x, unsigned* __restrict__ bits_z)
{
    int cn = blockIdx.x * 256 + threadIdx.x;
    if (cn >= NUM_CN) return;
    unsigned wx = 0, wz = 0;
#pragma unroll
    for (int b = 0; b < BATCH; ++b) {
        wx |= (unsigned)(syn_x[b * NUM_CN + cn] & 1) << b;
        wz |= (unsigned)(syn_z[b * NUM_CN + cn] & 1) << b;
    }
    bits_x[cn] = wx;
    bits_z[cn] = wz;
}

// ---------------------------------------------------------------------------
__device__ __forceinline__ unsigned pack_bf16(float a, float b) {
    unsigned ua = __float_as_uint(a); ua += 0x7fff + ((ua >> 16) & 1);
    unsigned ub = __float_as_uint(b); ub += 0x7fff + ((ub >> 16) & 1);
    return (ua >> 16) | (ub & 0xffff0000u);
}

// a1[ch][cn][b][32] = h_from[b,cn,:] @ W1[0:16,:]  bf16 lane-interleaved:
// per-cn block of 64 uint4; lane b's p-th uint4 at block + p*16 + b.
// ONLY change vs the 416us baseline: MASK FOLDED IN (validated R1/R2/R4,
// absmax identical) — syn==0 rows are written bf16 -inf so the gather-side
// relu(a1 + a2) == 0 reproduces mask*relu(...) with no per-edge bits load.
__global__ __launch_bounds__(256) void a1_kernel(
    const float* __restrict__ h_from_x, const float* __restrict__ h_from_z,
    const float* __restrict__ Wx1, const float* __restrict__ Wz1,
    const unsigned* __restrict__ bits_x, const unsigned* __restrict__ bits_z,
    uint4* __restrict__ a1x, uint4* __restrict__ a1z)
{
    int t = blockIdx.x * 256 + threadIdx.x;
    if (t >= NUM_CN * BATCH) return;
    const int ch = blockIdx.y;
    const int b  = t & 15;
    const int cn = t >> 4;
    const float* hsrc = (ch ? h_from_z : h_from_x) + ((size_t)b * NUM_CN + cn) * D_EMBED;
    const float* W1   = ch ? Wz1 : Wx1;
    const unsigned mw = (ch ? bits_z : bits_x)[cn];
    const bool on = (mw >> b) & 1u;
    uint4* dst = (ch ? a1z : a1x) + (size_t)cn * 64;

    float hf[D_EMBED];
#pragma unroll
    for (int i = 0; i < 4; ++i) {
        float4 v = ((const float4*)hsrc)[i];
        hf[4 * i + 0] = v.x; hf[4 * i + 1] = v.y;
        hf[4 * i + 2] = v.z; hf[4 * i + 3] = v.w;
    }
    float a[D_HIDDEN];
#pragma unroll
    for (int j = 0; j < D_HIDDEN; ++j) a[j] = 0.0f;
#pragma unroll
    for (int i = 0; i < D_EMBED; ++i) {
        const float fi = hf[i];
#pragma unroll
        for (int j = 0; j < D_HIDDEN; ++j)
            a[j] = fmaf(fi, W1[i * D_HIDDEN + j], a[j]);
    }
    unsigned u[16];
#pragma unroll
    for (int j = 0; j < 16; ++j)
        u[j] = on ? pack_bf16(a[2 * j], a[2 * j + 1]) : 0xFF80FF80u;
#pragma unroll
    for (int p = 0; p < 4; ++p) {
        uint4 q;
        q.x = u[4 * p + 0]; q.y = u[4 * p + 1];
        q.z = u[4 * p + 2]; q.w = u[4 * p + 3];
        dst[p * 16 + b] = q;
    }
}

// ---------------------------------------------------------------------------
// EXACT baseline gather structure (155us @ VGPR 76 / occ 29% / VALU 60%):
// thread=(n,b), single-edge loop, bf16 um staging to d_out, separate node
// kernel. Only delta vs baseline: mask comes pre-folded in a1 (-inf rows),
// so the per-edge bits load + fm mask FMA are deleted; hacc += fmax(...).
// Session rules encoded: NO min-wave pins (3x catastrophic spills), no
// 2-edge unroll (R4: VGPR 76->92, occ 29->20, 155->171us), no fusion (R1:
// occupancy drop outweighs traffic saved), no quarter/half split (R3/R5:
// more waves x same per-wave latency, or spills).
__device__ __forceinline__ void channel_accum(
    const float* __restrict__ h_to_slot, int n, int b,
    const int* __restrict__ off, const int* __restrict__ ids,
    const uint4* __restrict__ a1,
    const float* __restrict__ W1, const float* __restrict__ W2,
    unsigned* __restrict__ um)
{
    // reload ht per channel: 4 cache-hit loads < 16 live registers
    float ht[D_EMBED];
#pragma unroll
    for (int i = 0; i < 4; ++i) {
        float4 v = ((const float4*)h_to_slot)[i];
        ht[4 * i + 0] = v.x; ht[4 * i + 1] = v.y;
        ht[4 * i + 2] = v.z; ht[4 * i + 3] = v.w;
    }
    float2 a2[16];
#pragma unroll
    for (int p = 0; p < 16; ++p) { a2[p].x = 0.0f; a2[p].y = 0.0f; }
#pragma unroll
    for (int i = 0; i < D_EMBED; ++i) {
        const float hi = ht[i];
        const float* w = W1 + (D_EMBED + i) * D_HIDDEN;
#pragma unroll
        for (int p = 0; p < 16; ++p) {
            a2[p].x = fmaf(hi, w[2 * p],     a2[p].x);
            a2[p].y = fmaf(hi, w[2 * p + 1], a2[p].y);
        }
    }

    float2 hacc[16];
#pragma unroll
    for (int p = 0; p < 16; ++p) { hacc[p].x = 0.0f; hacc[p].y = 0.0f; }

    const int ks = off[n], ke = off[n + 1];
    for (int k = ks; k < ke; ++k) {
        const int from = ids[k];
        const uint4* pa = a1 + (size_t)from * 64 + b;
        uint4 q0 = pa[0], q1 = pa[16], q2 = pa[32], q3 = pa[48];
        unsigned uu[16] = {q0.x, q0.y, q0.z, q0.w,
                           q1.x, q1.y, q1.z, q1.w,
                           q2.x, q2.y, q2.z, q2.w,
                           q3.x, q3.y, q3.z, q3.w};
#pragma unroll
        for (int p = 0; p < 16; ++p) {
            float lo = __uint_as_float(uu[p] << 16);
            float hi = __uint_as_float(uu[p] & 0xffff0000u);
            hacc[p].x += fmaxf(a2[p].x + lo, 0.0f);
            hacc[p].y += fmaxf(a2[p].y + hi, 0.0f);
        }
    }

    float m[D_MSG];
#pragma unroll
    for (int j = 0; j < D_MSG; ++j) m[j] = 0.0f;
#pragma unroll
    for (int p = 0; p < 16; ++p) {
        const float h0 = hacc[p].x, h1 = hacc[p].y;
        const float* w0 = W2 + (2 * p) * D_MSG;
        const float* w1 = W2 + (2 * p + 1) * D_MSG;
#pragma unroll
        for (int j = 0; j < D_MSG; ++j)
            m[j] = fmaf(h0, w0[j], fmaf(h1, w1[j], m[j]));
    }
#pragma unroll
    for (int j = 0; j < 8; ++j) um[j] = pack_bf16(m[2 * j], m[2 * j + 1]);
}

// gather: thread=(n,b); writes packed bf16 {mx|mz} (64 B) into the thread's
// OWN final-output slot in d_out (node kernel reads then overwrites it).
__global__ __launch_bounds__(256) void gather_kernel(
    const float* __restrict__ h_to,
    const int* __restrict__ off_x, const int* __restrict__ ids_x,
    const int* __restrict__ off_z, const int* __restrict__ ids_z,
    const uint4* __restrict__ a1x, const uint4* __restrict__ a1z,
    const float* __restrict__ Wx1, const float* __restrict__ Wx2,
    const float* __restrict__ Wz1, const float* __restrict__ Wz2,
    uint4* __restrict__ out_m)
{
    const int t = blockIdx.x * 256 + threadIdx.x;
    if (t >= NUM_VN * BATCH) return;
    const int b = t & (BATCH - 1);
    const int n = t >> 4;
    const size_t slot = (size_t)b * NUM_VN + n;
    const float* ht_slot = h_to + slot * D_EMBED;

    unsigned um[16];
    channel_accum(ht_slot, n, b, off_x, ids_x, a1x, Wx1, Wx2, um);
    channel_accum(ht_slot, n, b, off_z, ids_z, a1z, Wz1, Wz2, um + 8);

    uint4* dst = out_m + slot * 4;
#pragma unroll
    for (int p = 0; p < 4; ++p) {
        uint4 q;
        q.x = um[4 * p + 0]; q.y = um[4 * p + 1];
        q.z = um[4 * p + 2]; q.w = um[4 * p + 3];
        dst[p] = q;
    }
}

// node MLP: reads its own slot {mx|mz} + h_to, computes 48->32(relu)->16,
// overwrites the slot with the final fp32 output. out is NOT __restrict__
// (deliberate read-then-write alias, same thread owns both).
__global__ __launch_bounds__(256) void node_kernel(
    const float* __restrict__ h_to,
    const float* __restrict__ We1, const float* __restrict__ We2,
    float* out)
{
    const int t = blockIdx.x * 256 + threadIdx.x;
    if (t >= NUM_VN * BATCH) return;
    const int b = t & (BATCH - 1);
    const int n = t >> 4;
    const size_t slot = (size_t)b * NUM_VN + n;

    const uint4* pm = (const uint4*)out + slot * 4;
    uint4 q0 = pm[0], q1 = pm[1], q2 = pm[2], q3 = pm[3];
    unsigned uu[16] = {q0.x, q0.y, q0.z, q0.w,
                       q1.x, q1.y, q1.z, q1.w,
                       q2.x, q2.y, q2.z, q2.w,
                       q3.x, q3.y, q3.z, q3.w};
    float f[48];
#pragma unroll
    for (int p = 0; p < 16; ++p) {
        f[2 * p]     = __uint_as_float(uu[p] << 16);
        f[2 * p + 1] = __uint_as_float(uu[p] & 0xffff0000u);
    }
#pragma unroll
    for (int i = 0; i < 4; ++i) {
        float4 v = ((const float4*)(h_to + slot * D_EMBED))[i];
        f[32 + 4 * i + 0] = v.x; f[32 + 4 * i + 1] = v.y;
        f[32 + 4 * i + 2] = v.z; f[32 + 4 * i + 3] = v.w;
    }

    float2 hid[16];
#pragma unroll
    for (int p = 0; p < 16; ++p) { hid[p].x = 0.0f; hid[p].y = 0.0f; }
#pragma unroll
    for (int i = 0; i < 48; ++i) {
        const float fi = f[i];
        const float* w = We1 + i * D_HIDDEN;
#pragma unroll
        for (int p = 0; p < 16; ++p) {
            hid[p].x = fmaf(fi, w[2 * p],     hid[p].x);
            hid[p].y = fmaf(fi, w[2 * p + 1], hid[p].y);
        }
    }
#pragma unroll
    for (int p = 0; p < 16; ++p) {
        hid[p].x = fmaxf(hid[p].x, 0.0f);
        hid[p].y = fmaxf(hid[p].y, 0.0f);
    }

    float o[D_EMBED];
#pragma unroll
    for (int k = 0; k < D_EMBED; ++k) o[k] = 0.0f;
#pragma unroll
    for (int p = 0; p < 16; ++p) {
        const float h0 = hid[p].x, h1 = hid[p].y;
        const float* w0 = We2 + (2 * p) * D_EMBED;
        const float* w1 = We2 + (2 * p + 1) * D_EMBED;
#pragma unroll
        for (int k = 0; k < D_EMBED; ++k)
            o[k] = fmaf(h0, w0[k], fmaf(h1, w1[k], o[k]));
    }

#pragma unroll
    for (int i = 0; i < 4; ++i) {
        float4 v;
        v.x = o[4 * i + 0]; v.y = o[4 * i + 1];
        v.z = o[4 * i + 2]; v.w = o[4 * i + 3];
        ((float4*)(out + slot * D_EMBED))[i] = v;
    }
}

// ---------------------------------------------------------------------------
extern "C" void kernel_launch(void* const* d_in, const int* in_sizes, int n_in,
                              void* d_out, int out_size, void* d_ws, size_t ws_size,
                              hipStream_t stream) {
    const float* h_from_x = (const float*)d_in[0];
    const float* h_from_z = (const float*)d_in[1];
    const float* h_to     = (const float*)d_in[2];
    const int*   syn_x    = (const int*)d_in[3];
    const int*   syn_z    = (const int*)d_in[4];
    const int*   fi_x     = (const int*)d_in[5];
    const int*   ti_x     = (const int*)d_in[6];
    const int*   fi_z     = (const int*)d_in[7];
    const int*   ti_z     = (const int*)d_in[8];
    const float* Wx1      = (const float*)d_in[9];
    const float* Wx2      = (const float*)d_in[10];
    const float* Wz1      = (const float*)d_in[11];
    const float* Wz2      = (const float*)d_in[12];
    const float* We1      = (const float*)d_in[13];
    const float* We2      = (const float*)d_in[14];

    int* ws = (int*)d_ws;
    int* ids_x  = ws + WS_IDS_X;
    int* ids_z  = ws + WS_IDS_Z;
    int* off_x  = ws + WS_OFF_X;
    int* off_z  = ws + WS_OFF_Z;
    int* cnt_x  = ws + WS_CNT_X;
    int* cnt_z  = ws + WS_CNT_Z;
    int* cur_x  = ws + WS_CUR_X;
    int* cur_z  = ws + WS_CUR_Z;
    int* incl_x = ws + WS_INCL_X;
    int* incl_z = ws + WS_INCL_Z;
    int* psum   = ws + WS_PSUM;
    int* base   = ws + WS_BASE;
    uint4* a1x  = (uint4*)(ws + WS_A1X);
    uint4* a1z  = (uint4*)(ws + WS_A1Z);

    // cur_* are dead after fill -> reuse as syndrome bitmasks
    unsigned* bits_x = (unsigned*)cur_x;
    unsigned* bits_z = (unsigned*)cur_z;

    hipMemsetAsync(cnt_x, 0, 2 * NUM_VN * sizeof(int), stream);

    hist_kernel<<<dim3((NUM_E + 255) / 256), dim3(256), 0, stream>>>(
        ti_x, ti_z, cnt_x, cnt_z);
    scan1_kernel<<<dim3(SCAN_CHUNKS, 2), dim3(1024), 0, stream>>>(
        cnt_x, cnt_z, incl_x, incl_z, psum);
    scan2_kernel<<<dim3(1), dim3(64), 0, stream>>>(psum, base);
    scan3_kernel<<<dim3(SCAN_CHUNKS, 2), dim3(1024), 0, stream>>>(
        cnt_x, cnt_z, incl_x, incl_z, base, off_x, off_z, cur_x, cur_z);
    fill_kernel<<<dim3((NUM_E + 255) / 256), dim3(256), 0, stream>>>(
        ti_x, ti_z, fi_x, fi_z, cur_x, cur_z, ids_x, ids_z);
    pack_bits_kernel<<<dim3((NUM_CN + 255) / 256), dim3(256), 0, stream>>>(
        syn_x, syn_z, bits_x, bits_z);

    a1_kernel<<<dim3((NUM_CN * BATCH + 255) / 256, 2), dim3(256), 0, stream>>>(
        h_from_x, h_from_z, Wx1, Wz1, bits_x, bits_z, a1x, a1z);

    gather_kernel<<<dim3((NUM_VN * BATCH) / 256), dim3(256), 0, stream>>>(
        h_to, off_x, ids_x, off_z, ids_z, a1x, a1z,
        Wx1, Wx2, Wz1, Wz2, (uint4*)d_out);

    node_kernel<<<dim3((NUM_VN * BATCH) / 256), dim3(256), 0, stream>>>(
        h_to, We1, We2, (float*)d_out);
}

// Round 8
// 384.278 us; speedup vs baseline: 2.1444x; 1.2158x over previous
//
#include <hip/hip_runtime.h>

#define NUM_CN   25000
#define NUM_VN   50000
#define NUM_E    200000
#define D_EMBED  16
#define D_HIDDEN 32
#define D_MSG    16
#define BATCH    16

typedef float f32x2 __attribute__((ext_vector_type(2)));

// ---------------------------------------------------------------------------
// Workspace layout (int units) — 54.41 MB total (proven available):
#define WS_IDS_X   0           // 200000  (stores FROM node ids, CSR order)
#define WS_IDS_Z   200000      // 200000
#define WS_OFF_X   400000      // 50001
#define WS_OFF_Z   450001      // 50001
#define WS_CNT_X   500002      // 50000
#define WS_CNT_Z   550002      // 50000
#define WS_CUR_X   600002      // 50000
#define WS_CUR_Z   650002      // 50000
#define WS_INCL_X  700002      // 51200
#define WS_INCL_Z  751202      // 51200
#define WS_PSUM    802402      // 128
#define WS_A1X     802816      // 6400000 ints = 25.6 MB bf16
#define WS_A1Z     7202816     // 6400000
#define SCAN_CHUNKS 49

// ---------------------------------------------------------------------------
__device__ __forceinline__ unsigned pack_bf16(float a, float b) {
    unsigned ua = __float_as_uint(a); ua += 0x7fff + ((ua >> 16) & 1);
    unsigned ub = __float_as_uint(b); ub += 0x7fff + ((ub >> 16) & 1);
    return (ua >> 16) | (ub & 0xffff0000u);
}

// MERGED hist + a1 (independent work, one launch; a1's FMA hides hist's
// atomic latency). blockIdx.y: 0 = hist, 1/2 = a1 channel 0/1.
// a1[ch][cn][b][32] = h_from[b,cn,:] @ W1[0:16,:] bf16 lane-interleaved:
// per-cn block of 64 uint4; lane b's p-th uint4 at block + p*16 + b.
// MASK FOLDED IN (validated R1/R2/R4/R6, absmax identical): syn==0 rows are
// bf16 -inf so gather-side relu(a1+a2)==0 == mask*relu(...). syn is read
// DIRECTLY here (1 int load/thread) -> pack_bits kernel deleted.
__global__ __launch_bounds__(256) void hist_a1_kernel(
    const int* __restrict__ ti_x, const int* __restrict__ ti_z,
    const float* __restrict__ h_from_x, const float* __restrict__ h_from_z,
    const int* __restrict__ syn_x, const int* __restrict__ syn_z,
    const float* __restrict__ Wx1, const float* __restrict__ Wz1,
    int* __restrict__ cnt_x, int* __restrict__ cnt_z,
    uint4* __restrict__ a1x, uint4* __restrict__ a1z)
{
    const int t = blockIdx.x * 256 + threadIdx.x;
    if (blockIdx.y == 0) {
        if (t < NUM_E) {
            atomicAdd(&cnt_x[ti_x[t]], 1);
            atomicAdd(&cnt_z[ti_z[t]], 1);
        }
        return;
    }
    if (t >= NUM_CN * BATCH) return;
    const int ch = blockIdx.y - 1;
    const int b  = t & 15;
    const int cn = t >> 4;
    const float* hsrc = (ch ? h_from_z : h_from_x) + ((size_t)b * NUM_CN + cn) * D_EMBED;
    const float* W1   = ch ? Wz1 : Wx1;
    const bool on = ((ch ? syn_z : syn_x)[b * NUM_CN + cn] & 1) != 0;
    uint4* dst = (ch ? a1z : a1x) + (size_t)cn * 64;

    float hf[D_EMBED];
#pragma unroll
    for (int i = 0; i < 4; ++i) {
        float4 v = ((const float4*)hsrc)[i];
        hf[4 * i + 0] = v.x; hf[4 * i + 1] = v.y;
        hf[4 * i + 2] = v.z; hf[4 * i + 3] = v.w;
    }
    f32x2 a[16] = {};
#pragma unroll
    for (int i = 0; i < D_EMBED; ++i) {
        const float fi = hf[i];
        const f32x2* wv = (const f32x2*)(W1 + i * D_HIDDEN);
#pragma unroll
        for (int j = 0; j < 16; ++j)
            a[j] = fi * wv[j] + a[j];        // v_pk_fma_f32 via contract
    }
    unsigned u[16];
#pragma unroll
    for (int j = 0; j < 16; ++j)
        u[j] = on ? pack_bf16(a[j].x, a[j].y) : 0xFF80FF80u;
#pragma unroll
    for (int p = 0; p < 4; ++p) {
        uint4 q;
        q.x = u[4 * p + 0]; q.y = u[4 * p + 1];
        q.z = u[4 * p + 2]; q.w = u[4 * p + 3];
        dst[p * 16 + b] = q;
    }
}

__global__ __launch_bounds__(1024) void scan1_kernel(
    const int* __restrict__ cnt_x, const int* __restrict__ cnt_z,
    int* __restrict__ incl_x, int* __restrict__ incl_z,
    int* __restrict__ psum)
{
    __shared__ int s[1024];
    const int ch  = blockIdx.y;
    const int blk = blockIdx.x;
    const int t   = threadIdx.x;
    const int gid = blk * 1024 + t;
    const int* cnt  = ch ? cnt_z  : cnt_x;
    int*       incl = ch ? incl_z : incl_x;
    int v = (gid < NUM_VN) ? cnt[gid] : 0;
    s[t] = v;
    __syncthreads();
#pragma unroll
    for (int d = 1; d < 1024; d <<= 1) {
        int x = 0;
        if (t >= d) x = s[t - d];
        __syncthreads();
        if (t >= d) s[t] += x;
        __syncthreads();
    }
    incl[gid] = s[t];
    if (t == 1023) psum[ch * 64 + blk] = s[1023];
}

// scan3 with scan2 inlined: thread 0 sums psum[0..blk) (<=48 adds) into
// shared, broadcast. Saves one launch.
__global__ __launch_bounds__(1024) void scan3_kernel(
    const int* __restrict__ cnt_x, const int* __restrict__ cnt_z,
    const int* __restrict__ incl_x, const int* __restrict__ incl_z,
    const int* __restrict__ psum,
    int* __restrict__ off_x, int* __restrict__ off_z,
    int* __restrict__ cur_x, int* __restrict__ cur_z)
{
    const int ch  = blockIdx.y;
    const int blk = blockIdx.x;
    const int t   = threadIdx.x;
    __shared__ int sbase;
    if (t == 0) {
        int run = 0;
        for (int i = 0; i < blk; ++i) run += psum[ch * 64 + i];
        sbase = run;
    }
    __syncthreads();
    const int i = blk * 1024 + t;
    if (i >= NUM_VN) return;
    const int* cnt  = ch ? cnt_z  : cnt_x;
    const int* incl = ch ? incl_z : incl_x;
    int*       off  = ch ? off_z  : off_x;
    int*       cur  = ch ? cur_z  : cur_x;
    int bs = sbase;
    int iv = incl[i];
    off[i + 1] = bs + iv;
    cur[i]     = bs + iv - cnt[i];
    if (i == 0) off[0] = 0;
}

// fill: CSR slot stores the FROM node id directly.
__global__ __launch_bounds__(256) void fill_kernel(
    const int* __restrict__ ti_x, const int* __restrict__ ti_z,
    const int* __restrict__ fi_x, const int* __restrict__ fi_z,
    int* __restrict__ cur_x, int* __restrict__ cur_z,
    int* __restrict__ ids_x, int* __restrict__ ids_z)
{
    int e = blockIdx.x * 256 + threadIdx.x;
    if (e >= NUM_E) return;
    int px = atomicAdd(&cur_x[ti_x[e]], 1);
    ids_x[px] = fi_x[e];
    int pz = atomicAdd(&cur_z[ti_z[e]], 1);
    ids_z[pz] = fi_z[e];
}

// ---------------------------------------------------------------------------
// Baseline gather structure (153us proven) with PACKED-FP32 arithmetic:
// all three FMA sections on f32x2 (<2 x float> -> v_pk_fma_f32/v_pk_add_f32,
// gfx950 VOP3P). Accumulator state unchanged (32 floats as 16 reg pairs) so
// liveness/occupancy should hold. Session rules: NO min-wave pins (3x
// catastrophic spills), single-edge loop (R4: unroll cost occupancy), no
// fusion, no split.
__device__ __forceinline__ void channel_accum(
    const float* __restrict__ h_to_slot, int n, int b,
    const int* __restrict__ off, const int* __restrict__ ids,
    const uint4* __restrict__ a1,
    const float* __restrict__ W1, const float* __restrict__ W2,
    unsigned* __restrict__ um)
{
    const f32x2 z2 = {0.0f, 0.0f};
    // reload ht per channel: 4 cache-hit loads < 16 live registers
    float ht[D_EMBED];
#pragma unroll
    for (int i = 0; i < 4; ++i) {
        float4 v = ((const float4*)h_to_slot)[i];
        ht[4 * i + 0] = v.x; ht[4 * i + 1] = v.y;
        ht[4 * i + 2] = v.z; ht[4 * i + 3] = v.w;
    }
    f32x2 a2[16] = {};
#pragma unroll
    for (int i = 0; i < D_EMBED; ++i) {
        const float hi = ht[i];
        const f32x2* wv = (const f32x2*)(W1 + (D_EMBED + i) * D_HIDDEN);
#pragma unroll
        for (int p = 0; p < 16; ++p)
            a2[p] = hi * wv[p] + a2[p];          // pk_fma
    }

    f32x2 hacc[16] = {};

    const int ks = off[n], ke = off[n + 1];
    for (int k = ks; k < ke; ++k) {
        const int from = ids[k];
        const uint4* pa = a1 + (size_t)from * 64 + b;
        uint4 q0 = pa[0], q1 = pa[16], q2 = pa[32], q3 = pa[48];
        unsigned uu[16] = {q0.x, q0.y, q0.z, q0.w,
                           q1.x, q1.y, q1.z, q1.w,
                           q2.x, q2.y, q2.z, q2.w,
                           q3.x, q3.y, q3.z, q3.w};
#pragma unroll
        for (int p = 0; p < 16; ++p) {
            f32x2 v;
            v.x = __uint_as_float(uu[p] << 16);
            v.y = __uint_as_float(uu[p] & 0xffff0000u);
            f32x2 s = a2[p] + v;                  // pk_add
            s = __builtin_elementwise_max(s, z2); // max (pk or 2x scalar)
            hacc[p] += s;                         // pk_add
        }
    }

    f32x2 m2[8] = {};
#pragma unroll
    for (int p = 0; p < 16; ++p) {
        const float h0 = hacc[p].x, h1 = hacc[p].y;
        const f32x2* w0 = (const f32x2*)(W2 + (2 * p) * D_MSG);
        const f32x2* w1 = (const f32x2*)(W2 + (2 * p + 1) * D_MSG);
#pragma unroll
        for (int j = 0; j < 8; ++j)
            m2[j] = h0 * w0[j] + (h1 * w1[j] + m2[j]);   // 2x pk_fma
    }
#pragma unroll
    for (int j = 0; j < 8; ++j) um[j] = pack_bf16(m2[j].x, m2[j].y);
}

// gather: thread=(n,b); writes packed bf16 {mx|mz} (64 B) into the thread's
// OWN final-output slot in d_out (node kernel reads then overwrites it).
__global__ __launch_bounds__(256) void gather_kernel(
    const float* __restrict__ h_to,
    const int* __restrict__ off_x, const int* __restrict__ ids_x,
    const int* __restrict__ off_z, const int* __restrict__ ids_z,
    const uint4* __restrict__ a1x, const uint4* __restrict__ a1z,
    const float* __restrict__ Wx1, const float* __restrict__ Wx2,
    const float* __restrict__ Wz1, const float* __restrict__ Wz2,
    uint4* __restrict__ out_m)
{
    const int t = blockIdx.x * 256 + threadIdx.x;
    if (t >= NUM_VN * BATCH) return;
    const int b = t & (BATCH - 1);
    const int n = t >> 4;
    const size_t slot = (size_t)b * NUM_VN + n;
    const float* ht_slot = h_to + slot * D_EMBED;

    unsigned um[16];
    channel_accum(ht_slot, n, b, off_x, ids_x, a1x, Wx1, Wx2, um);
    channel_accum(ht_slot, n, b, off_z, ids_z, a1z, Wz1, Wz2, um + 8);

    uint4* dst = out_m + slot * 4;
#pragma unroll
    for (int p = 0; p < 4; ++p) {
        uint4 q;
        q.x = um[4 * p + 0]; q.y = um[4 * p + 1];
        q.z = um[4 * p + 2]; q.w = um[4 * p + 3];
        dst[p] = q;
    }
}

// node MLP: reads its own slot {mx|mz} + h_to, computes 48->32(relu)->16,
// overwrites the slot with the final fp32 output. Packed-fp32 variant.
__global__ __launch_bounds__(256) void node_kernel(
    const float* __restrict__ h_to,
    const float* __restrict__ We1, const float* __restrict__ We2,
    float* out)
{
    const f32x2 z2 = {0.0f, 0.0f};
    const int t = blockIdx.x * 256 + threadIdx.x;
    if (t >= NUM_VN * BATCH) return;
    const int b = t & (BATCH - 1);
    const int n = t >> 4;
    const size_t slot = (size_t)b * NUM_VN + n;

    const uint4* pm = (const uint4*)out + slot * 4;
    uint4 q0 = pm[0], q1 = pm[1], q2 = pm[2], q3 = pm[3];
    unsigned uu[16] = {q0.x, q0.y, q0.z, q0.w,
                       q1.x, q1.y, q1.z, q1.w,
                       q2.x, q2.y, q2.z, q2.w,
                       q3.x, q3.y, q3.z, q3.w};
    float f[48];
#pragma unroll
    for (int p = 0; p < 16; ++p) {
        f[2 * p]     = __uint_as_float(uu[p] << 16);
        f[2 * p + 1] = __uint_as_float(uu[p] & 0xffff0000u);
    }
#pragma unroll
    for (int i = 0; i < 4; ++i) {
        float4 v = ((const float4*)(h_to + slot * D_EMBED))[i];
        f[32 + 4 * i + 0] = v.x; f[32 + 4 * i + 1] = v.y;
        f[32 + 4 * i + 2] = v.z; f[32 + 4 * i + 3] = v.w;
    }

    f32x2 hid[16] = {};
#pragma unroll
    for (int i = 0; i < 48; ++i) {
        const float fi = f[i];
        const f32x2* wv = (const f32x2*)(We1 + i * D_HIDDEN);
#pragma unroll
        for (int p = 0; p < 16; ++p)
            hid[p] = fi * wv[p] + hid[p];
    }
#pragma unroll
    for (int p = 0; p < 16; ++p)
        hid[p] = __builtin_elementwise_max(hid[p], z2);

    f32x2 o2[8] = {};
#pragma unroll
    for (int p = 0; p < 16; ++p) {
        const float h0 = hid[p].x, h1 = hid[p].y;
        const f32x2* w0 = (const f32x2*)(We2 + (2 * p) * D_EMBED);
        const f32x2* w1 = (const f32x2*)(We2 + (2 * p + 1) * D_EMBED);
#pragma unroll
        for (int j = 0; j < 8; ++j)
            o2[j] = h0 * w0[j] + (h1 * w1[j] + o2[j]);
    }

#pragma unroll
    for (int i = 0; i < 4; ++i) {
        float4 v;
        v.x = o2[2 * i].x;     v.y = o2[2 * i].y;
        v.z = o2[2 * i + 1].x; v.w = o2[2 * i + 1].y;
        ((float4*)(out + slot * D_EMBED))[i] = v;
    }
}

// ---------------------------------------------------------------------------
extern "C" void kernel_launch(void* const* d_in, const int* in_sizes, int n_in,
                              void* d_out, int out_size, void* d_ws, size_t ws_size,
                              hipStream_t stream) {
    const float* h_from_x = (const float*)d_in[0];
    const float* h_from_z = (const float*)d_in[1];
    const float* h_to     = (const float*)d_in[2];
    const int*   syn_x    = (const int*)d_in[3];
    const int*   syn_z    = (const int*)d_in[4];
    const int*   fi_x     = (const int*)d_in[5];
    const int*   ti_x     = (const int*)d_in[6];
    const int*   fi_z     = (const int*)d_in[7];
    const int*   ti_z     = (const int*)d_in[8];
    const float* Wx1      = (const float*)d_in[9];
    const float* Wx2      = (const float*)d_in[10];
    const float* Wz1      = (const float*)d_in[11];
    const float* Wz2      = (const float*)d_in[12];
    const float* We1      = (const float*)d_in[13];
    const float* We2      = (const float*)d_in[14];

    int* ws = (int*)d_ws;
    int* ids_x  = ws + WS_IDS_X;
    int* ids_z  = ws + WS_IDS_Z;
    int* off_x  = ws + WS_OFF_X;
    int* off_z  = ws + WS_OFF_Z;
    int* cnt_x  = ws + WS_CNT_X;
    int* cnt_z  = ws + WS_CNT_Z;
    int* cur_x  = ws + WS_CUR_X;
    int* cur_z  = ws + WS_CUR_Z;
    int* incl_x = ws + WS_INCL_X;
    int* incl_z = ws + WS_INCL_Z;
    int* psum   = ws + WS_PSUM;
    uint4* a1x  = (uint4*)(ws + WS_A1X);
    uint4* a1z  = (uint4*)(ws + WS_A1Z);

    hipMemsetAsync(cnt_x, 0, 2 * NUM_VN * sizeof(int), stream);

    // hist + a1 in one launch (independent; y=0 hist, y=1/2 a1 ch0/ch1)
    hist_a1_kernel<<<dim3((NUM_CN * BATCH + 255) / 256, 3), dim3(256), 0, stream>>>(
        ti_x, ti_z, h_from_x, h_from_z, syn_x, syn_z, Wx1, Wz1,
        cnt_x, cnt_z, a1x, a1z);
    scan1_kernel<<<dim3(SCAN_CHUNKS, 2), dim3(1024), 0, stream>>>(
        cnt_x, cnt_z, incl_x, incl_z, psum);
    scan3_kernel<<<dim3(SCAN_CHUNKS, 2), dim3(1024), 0, stream>>>(
        cnt_x, cnt_z, incl_x, incl_z, psum, off_x, off_z, cur_x, cur_z);
    fill_kernel<<<dim3((NUM_E + 255) / 256), dim3(256), 0, stream>>>(
        ti_x, ti_z, fi_x, fi_z, cur_x, cur_z, ids_x, ids_z);

    gather_kernel<<<dim3((NUM_VN * BATCH) / 256), dim3(256), 0, stream>>>(
        h_to, off_x, ids_x, off_z, ids_z, a1x, a1z,
        Wx1, Wx2, Wz1, Wz2, (uint4*)d_out);

    node_kernel<<<dim3((NUM_VN * BATCH) / 256), dim3(256), 0, stream>>>(
        h_to, We1, We2, (float*)d_out);
}

// Round 9
// 361.056 us; speedup vs baseline: 2.2823x; 1.0643x over previous
//
#include <hip/hip_runtime.h>

#define NUM_CN   25000
#define NUM_VN   50000
#define NUM_E    200000
#define D_EMBED  16
#define D_HIDDEN 32
#define D_MSG    16
#define BATCH    16

typedef float f32x2 __attribute__((ext_vector_type(2)));

// ---------------------------------------------------------------------------
// Workspace layout (int units) — 54.41 MB total (proven available):
#define WS_IDS_X   0           // 200000  (stores FROM node ids, CSR order)
#define WS_IDS_Z   200000      // 200000
#define WS_OFF_X   400000      // 50001
#define WS_OFF_Z   450001      // 50001
#define WS_CNT_X   500002      // 50000
#define WS_CNT_Z   550002      // 50000
#define WS_CUR_X   600002      // 50000
#define WS_CUR_Z   650002      // 50000
#define WS_INCL_X  700002      // 51200
#define WS_INCL_Z  751202      // 51200
#define WS_PSUM    802402      // 128
#define WS_A1X     802816      // 6400000 ints = 25.6 MB bf16
#define WS_A1Z     7202816     // 6400000
#define SCAN_CHUNKS 49

// ---------------------------------------------------------------------------
__device__ __forceinline__ unsigned pack_bf16(float a, float b) {
    unsigned ua = __float_as_uint(a); ua += 0x7fff + ((ua >> 16) & 1);
    unsigned ub = __float_as_uint(b); ub += 0x7fff + ((ub >> 16) & 1);
    return (ua >> 16) | (ub & 0xffff0000u);
}

// MERGED hist + a1 (independent work, one launch; a1's FMA hides hist's
// atomic latency). blockIdx.y: 0 = hist, 1/2 = a1 channel 0/1.
// a1[ch][cn][b][32] = h_from[b,cn,:] @ W1[0:16,:] bf16 lane-interleaved:
// per-cn block of 64 uint4; lane b's p-th uint4 at block + p*16 + b.
// MASK FOLDED IN (validated R1/R2/R4/R6/R7): syn==0 rows are bf16 -inf so
// gather-side relu(a1+a2)==0 == mask*relu(...).
__global__ __launch_bounds__(256) void hist_a1_kernel(
    const int* __restrict__ ti_x, const int* __restrict__ ti_z,
    const float* __restrict__ h_from_x, const float* __restrict__ h_from_z,
    const int* __restrict__ syn_x, const int* __restrict__ syn_z,
    const float* __restrict__ Wx1, const float* __restrict__ Wz1,
    int* __restrict__ cnt_x, int* __restrict__ cnt_z,
    uint4* __restrict__ a1x, uint4* __restrict__ a1z)
{
    const int t = blockIdx.x * 256 + threadIdx.x;
    if (blockIdx.y == 0) {
        if (t < NUM_E) {
            atomicAdd(&cnt_x[ti_x[t]], 1);
            atomicAdd(&cnt_z[ti_z[t]], 1);
        }
        return;
    }
    if (t >= NUM_CN * BATCH) return;
    const int ch = blockIdx.y - 1;
    const int b  = t & 15;
    const int cn = t >> 4;
    const float* hsrc = (ch ? h_from_z : h_from_x) + ((size_t)b * NUM_CN + cn) * D_EMBED;
    const float* W1   = ch ? Wz1 : Wx1;
    const bool on = ((ch ? syn_z : syn_x)[b * NUM_CN + cn] & 1) != 0;
    uint4* dst = (ch ? a1z : a1x) + (size_t)cn * 64;

    float hf[D_EMBED];
#pragma unroll
    for (int i = 0; i < 4; ++i) {
        float4 v = ((const float4*)hsrc)[i];
        hf[4 * i + 0] = v.x; hf[4 * i + 1] = v.y;
        hf[4 * i + 2] = v.z; hf[4 * i + 3] = v.w;
    }
    f32x2 a[16] = {};
#pragma unroll
    for (int i = 0; i < D_EMBED; ++i) {
        const float fi = hf[i];
        const f32x2* wv = (const f32x2*)(W1 + i * D_HIDDEN);
#pragma unroll
        for (int j = 0; j < 16; ++j)
            a[j] = fi * wv[j] + a[j];        // v_pk_fma_f32 via contract
    }
    unsigned u[16];
#pragma unroll
    for (int j = 0; j < 16; ++j)
        u[j] = on ? pack_bf16(a[j].x, a[j].y) : 0xFF80FF80u;
#pragma unroll
    for (int p = 0; p < 4; ++p) {
        uint4 q;
        q.x = u[4 * p + 0]; q.y = u[4 * p + 1];
        q.z = u[4 * p + 2]; q.w = u[4 * p + 3];
        dst[p * 16 + b] = q;
    }
}

__global__ __launch_bounds__(1024) void scan1_kernel(
    const int* __restrict__ cnt_x, const int* __restrict__ cnt_z,
    int* __restrict__ incl_x, int* __restrict__ incl_z,
    int* __restrict__ psum)
{
    __shared__ int s[1024];
    const int ch  = blockIdx.y;
    const int blk = blockIdx.x;
    const int t   = threadIdx.x;
    const int gid = blk * 1024 + t;
    const int* cnt  = ch ? cnt_z  : cnt_x;
    int*       incl = ch ? incl_z : incl_x;
    int v = (gid < NUM_VN) ? cnt[gid] : 0;
    s[t] = v;
    __syncthreads();
#pragma unroll
    for (int d = 1; d < 1024; d <<= 1) {
        int x = 0;
        if (t >= d) x = s[t - d];
        __syncthreads();
        if (t >= d) s[t] += x;
        __syncthreads();
    }
    incl[gid] = s[t];
    if (t == 1023) psum[ch * 64 + blk] = s[1023];
}

// scan3 with scan2 inlined: thread 0 sums psum[0..blk) (<=48 adds) into
// shared, broadcast. Saves one launch.
__global__ __launch_bounds__(1024) void scan3_kernel(
    const int* __restrict__ cnt_x, const int* __restrict__ cnt_z,
    const int* __restrict__ incl_x, const int* __restrict__ incl_z,
    const int* __restrict__ psum,
    int* __restrict__ off_x, int* __restrict__ off_z,
    int* __restrict__ cur_x, int* __restrict__ cur_z)
{
    const int ch  = blockIdx.y;
    const int blk = blockIdx.x;
    const int t   = threadIdx.x;
    __shared__ int sbase;
    if (t == 0) {
        int run = 0;
        for (int i = 0; i < blk; ++i) run += psum[ch * 64 + i];
        sbase = run;
    }
    __syncthreads();
    const int i = blk * 1024 + t;
    if (i >= NUM_VN) return;
    const int* cnt  = ch ? cnt_z  : cnt_x;
    const int* incl = ch ? incl_z : incl_x;
    int*       off  = ch ? off_z  : off_x;
    int*       cur  = ch ? cur_z  : cur_x;
    int bs = sbase;
    int iv = incl[i];
    off[i + 1] = bs + iv;
    cur[i]     = bs + iv - cnt[i];
    if (i == 0) off[0] = 0;
}

// fill: CSR slot stores the FROM node id directly.
__global__ __launch_bounds__(256) void fill_kernel(
    const int* __restrict__ ti_x, const int* __restrict__ ti_z,
    const int* __restrict__ fi_x, const int* __restrict__ fi_z,
    int* __restrict__ cur_x, int* __restrict__ cur_z,
    int* __restrict__ ids_x, int* __restrict__ ids_z)
{
    int e = blockIdx.x * 256 + threadIdx.x;
    if (e >= NUM_E) return;
    int px = atomicAdd(&cur_x[ti_x[e]], 1);
    ids_x[px] = fi_x[e];
    int pz = atomicAdd(&cur_z[ti_z[e]], 1);
    ids_z[pz] = fi_z[e];
}

// ---------------------------------------------------------------------------
// Gather (137us @ VGPR 68 proven, packed-fp32). THIS ROUND'S single change:
// each channel packs + STORES its message immediately (dst[0..1] after X,
// dst[2..3] after Z) so no um[] crosses the channel boundary — peak live set
// during the Z edge loop drops ~8 regs, targeting the 64-VGPR / 8-wave tier
// WITHOUT a pin (session rule: pins = catastrophic spills, n=3).
// Session rules: single-edge loop (R4), no fusion (R1), no split (R3/R5).
__device__ __forceinline__ void acc4(
    unsigned w0, unsigned w1, unsigned w2, unsigned w3,
    const f32x2* __restrict__ a2, f32x2* __restrict__ hacc)
{
    const f32x2 z2 = {0.0f, 0.0f};
    unsigned ww[4] = {w0, w1, w2, w3};
#pragma unroll
    for (int j = 0; j < 4; ++j) {
        f32x2 v;
        v.x = __uint_as_float(ww[j] << 16);
        v.y = __uint_as_float(ww[j] & 0xffff0000u);
        f32x2 s = a2[j] + v;                  // pk_add
        s = __builtin_elementwise_max(s, z2); // pk_max
        hacc[j] += s;                         // pk_add
    }
}

__device__ __forceinline__ void channel_accum_store(
    const float* __restrict__ h_to_slot, int n, int b,
    const int* __restrict__ off, const int* __restrict__ ids,
    const uint4* __restrict__ a1,
    const float* __restrict__ W1, const float* __restrict__ W2,
    uint4* __restrict__ dst2)   // writes dst2[0], dst2[1]
{
    // reload ht per channel: 4 cache-hit loads < 16 live registers
    float ht[D_EMBED];
#pragma unroll
    for (int i = 0; i < 4; ++i) {
        float4 v = ((const float4*)h_to_slot)[i];
        ht[4 * i + 0] = v.x; ht[4 * i + 1] = v.y;
        ht[4 * i + 2] = v.z; ht[4 * i + 3] = v.w;
    }
    f32x2 a2[16] = {};
#pragma unroll
    for (int i = 0; i < D_EMBED; ++i) {
        const float hi = ht[i];
        const f32x2* wv = (const f32x2*)(W1 + (D_EMBED + i) * D_HIDDEN);
#pragma unroll
        for (int p = 0; p < 16; ++p)
            a2[p] = hi * wv[p] + a2[p];          // pk_fma
    }

    f32x2 hacc[16] = {};

    const int ks = off[n], ke = off[n + 1];
    for (int k = ks; k < ke; ++k) {
        const uint4* pa = a1 + (size_t)ids[k] * 64 + b;
        uint4 q0 = pa[0], q1 = pa[16], q2 = pa[32], q3 = pa[48];
        acc4(q0.x, q0.y, q0.z, q0.w, a2 + 0,  hacc + 0);
        acc4(q1.x, q1.y, q1.z, q1.w, a2 + 4,  hacc + 4);
        acc4(q2.x, q2.y, q2.z, q2.w, a2 + 8,  hacc + 8);
        acc4(q3.x, q3.y, q3.z, q3.w, a2 + 12, hacc + 12);
    }

    f32x2 m2[8] = {};
#pragma unroll
    for (int p = 0; p < 16; ++p) {
        const float h0 = hacc[p].x, h1 = hacc[p].y;
        const f32x2* w0 = (const f32x2*)(W2 + (2 * p) * D_MSG);
        const f32x2* w1 = (const f32x2*)(W2 + (2 * p + 1) * D_MSG);
#pragma unroll
        for (int j = 0; j < 8; ++j)
            m2[j] = h0 * w0[j] + (h1 * w1[j] + m2[j]);   // 2x pk_fma
    }
    uint4 q;
    q.x = pack_bf16(m2[0].x, m2[0].y); q.y = pack_bf16(m2[1].x, m2[1].y);
    q.z = pack_bf16(m2[2].x, m2[2].y); q.w = pack_bf16(m2[3].x, m2[3].y);
    dst2[0] = q;
    q.x = pack_bf16(m2[4].x, m2[4].y); q.y = pack_bf16(m2[5].x, m2[5].y);
    q.z = pack_bf16(m2[6].x, m2[6].y); q.w = pack_bf16(m2[7].x, m2[7].y);
    dst2[1] = q;
}

// gather: thread=(n,b); writes packed bf16 {mx|mz} (64 B) into the thread's
// OWN final-output slot in d_out (node kernel reads then overwrites it).
__global__ __launch_bounds__(256) void gather_kernel(
    const float* __restrict__ h_to,
    const int* __restrict__ off_x, const int* __restrict__ ids_x,
    const int* __restrict__ off_z, const int* __restrict__ ids_z,
    const uint4* __restrict__ a1x, const uint4* __restrict__ a1z,
    const float* __restrict__ Wx1, const float* __restrict__ Wx2,
    const float* __restrict__ Wz1, const float* __restrict__ Wz2,
    uint4* __restrict__ out_m)
{
    const int t = blockIdx.x * 256 + threadIdx.x;
    if (t >= NUM_VN * BATCH) return;
    const int b = t & (BATCH - 1);
    const int n = t >> 4;
    const size_t slot = (size_t)b * NUM_VN + n;
    const float* ht_slot = h_to + slot * D_EMBED;
    uint4* dst = out_m + slot * 4;

    channel_accum_store(ht_slot, n, b, off_x, ids_x, a1x, Wx1, Wx2, dst);
    channel_accum_store(ht_slot, n, b, off_z, ids_z, a1z, Wz1, Wz2, dst + 2);
}

// node MLP: reads its own slot {mx|mz} + h_to, computes 48->32(relu)->16,
// overwrites the slot with the final fp32 output. Packed-fp32 variant.
__global__ __launch_bounds__(256) void node_kernel(
    const float* __restrict__ h_to,
    const float* __restrict__ We1, const float* __restrict__ We2,
    float* out)
{
    const f32x2 z2 = {0.0f, 0.0f};
    const int t = blockIdx.x * 256 + threadIdx.x;
    if (t >= NUM_VN * BATCH) return;
    const int b = t & (BATCH - 1);
    const int n = t >> 4;
    const size_t slot = (size_t)b * NUM_VN + n;

    const uint4* pm = (const uint4*)out + slot * 4;
    uint4 q0 = pm[0], q1 = pm[1], q2 = pm[2], q3 = pm[3];
    unsigned uu[16] = {q0.x, q0.y, q0.z, q0.w,
                       q1.x, q1.y, q1.z, q1.w,
                       q2.x, q2.y, q2.z, q2.w,
                       q3.x, q3.y, q3.z, q3.w};
    float f[48];
#pragma unroll
    for (int p = 0; p < 16; ++p) {
        f[2 * p]     = __uint_as_float(uu[p] << 16);
        f[2 * p + 1] = __uint_as_float(uu[p] & 0xffff0000u);
    }
#pragma unroll
    for (int i = 0; i < 4; ++i) {
        float4 v = ((const float4*)(h_to + slot * D_EMBED))[i];
        f[32 + 4 * i + 0] = v.x; f[32 + 4 * i + 1] = v.y;
        f[32 + 4 * i + 2] = v.z; f[32 + 4 * i + 3] = v.w;
    }

    f32x2 hid[16] = {};
#pragma unroll
    for (int i = 0; i < 48; ++i) {
        const float fi = f[i];
        const f32x2* wv = (const f32x2*)(We1 + i * D_HIDDEN);
#pragma unroll
        for (int p = 0; p < 16; ++p)
            hid[p] = fi * wv[p] + hid[p];
    }
#pragma unroll
    for (int p = 0; p < 16; ++p)
        hid[p] = __builtin_elementwise_max(hid[p], z2);

    f32x2 o2[8] = {};
#pragma unroll
    for (int p = 0; p < 16; ++p) {
        const float h0 = hid[p].x, h1 = hid[p].y;
        const f32x2* w0 = (const f32x2*)(We2 + (2 * p) * D_EMBED);
        const f32x2* w1 = (const f32x2*)(We2 + (2 * p + 1) * D_EMBED);
#pragma unroll
        for (int j = 0; j < 8; ++j)
            o2[j] = h0 * w0[j] + (h1 * w1[j] + o2[j]);
    }

#pragma unroll
    for (int i = 0; i < 4; ++i) {
        float4 v;
        v.x = o2[2 * i].x;     v.y = o2[2 * i].y;
        v.z = o2[2 * i + 1].x; v.w = o2[2 * i + 1].y;
        ((float4*)(out + slot * D_EMBED))[i] = v;
    }
}

// ---------------------------------------------------------------------------
extern "C" void kernel_launch(void* const* d_in, const int* in_sizes, int n_in,
                              void* d_out, int out_size, void* d_ws, size_t ws_size,
                              hipStream_t stream) {
    const float* h_from_x = (const float*)d_in[0];
    const float* h_from_z = (const float*)d_in[1];
    const float* h_to     = (const float*)d_in[2];
    const int*   syn_x    = (const int*)d_in[3];
    const int*   syn_z    = (const int*)d_in[4];
    const int*   fi_x     = (const int*)d_in[5];
    const int*   ti_x     = (const int*)d_in[6];
    const int*   fi_z     = (const int*)d_in[7];
    const int*   ti_z     = (const int*)d_in[8];
    const float* Wx1      = (const float*)d_in[9];
    const float* Wx2      = (const float*)d_in[10];
    const float* Wz1      = (const float*)d_in[11];
    const float* Wz2      = (const float*)d_in[12];
    const float* We1      = (const float*)d_in[13];
    const float* We2      = (const float*)d_in[14];

    int* ws = (int*)d_ws;
    int* ids_x  = ws + WS_IDS_X;
    int* ids_z  = ws + WS_IDS_Z;
    int* off_x  = ws + WS_OFF_X;
    int* off_z  = ws + WS_OFF_Z;
    int* cnt_x  = ws + WS_CNT_X;
    int* cnt_z  = ws + WS_CNT_Z;
    int* cur_x  = ws + WS_CUR_X;
    int* cur_z  = ws + WS_CUR_Z;
    int* incl_x = ws + WS_INCL_X;
    int* incl_z = ws + WS_INCL_Z;
    int* psum   = ws + WS_PSUM;
    uint4* a1x  = (uint4*)(ws + WS_A1X);
    uint4* a1z  = (uint4*)(ws + WS_A1Z);

    hipMemsetAsync(cnt_x, 0, 2 * NUM_VN * sizeof(int), stream);

    // hist + a1 in one launch (independent; y=0 hist, y=1/2 a1 ch0/ch1)
    hist_a1_kernel<<<dim3((NUM_CN * BATCH + 255) / 256, 3), dim3(256), 0, stream>>>(
        ti_x, ti_z, h_from_x, h_from_z, syn_x, syn_z, Wx1, Wz1,
        cnt_x, cnt_z, a1x, a1z);
    scan1_kernel<<<dim3(SCAN_CHUNKS, 2), dim3(1024), 0, stream>>>(
        cnt_x, cnt_z, incl_x, incl_z, psum);
    scan3_kernel<<<dim3(SCAN_CHUNKS, 2), dim3(1024), 0, stream>>>(
        cnt_x, cnt_z, incl_x, incl_z, psum, off_x, off_z, cur_x, cur_z);
    fill_kernel<<<dim3((NUM_E + 255) / 256), dim3(256), 0, stream>>>(
        ti_x, ti_z, fi_x, fi_z, cur_x, cur_z, ids_x, ids_z);

    gather_kernel<<<dim3((NUM_VN * BATCH) / 256), dim3(256), 0, stream>>>(
        h_to, off_x, ids_x, off_z, ids_z, a1x, a1z,
        Wx1, Wx2, Wz1, Wz2, (uint4*)d_out);

    node_kernel<<<dim3((NUM_VN * BATCH) / 256), dim3(256), 0, stream>>>(
        h_to, We1, We2, (float*)d_out);
}